// Round 15
// baseline (280.585 us; speedup 1.0000x reference)
//
#include <hip/hip_runtime.h>

#define SEQ 2048
#define DIM 512
#define NBATCH 32
#define NH 16
#define HDIM 32
#define NCLS 2

typedef __attribute__((ext_vector_type(8))) short short8;
typedef __attribute__((ext_vector_type(8))) unsigned short ushort8;
typedef __attribute__((ext_vector_type(4))) float f32x4;

__device__ __forceinline__ float b2f(unsigned short u){
  union { unsigned int i; float f; } v; v.i = ((unsigned int)u) << 16; return v.f;
}
__device__ __forceinline__ unsigned short f2b(float f){
  unsigned int x = __float_as_uint(f);
  unsigned int r = (x + 0x7fffu + ((x >> 16) & 1u)) >> 16;
  return (unsigned short)r;
}
__device__ __forceinline__ void gload16(const void* g, void* l){
  __builtin_amdgcn_global_load_lds((const __attribute__((address_space(1))) void*)g,
                                   (__attribute__((address_space(3))) void*)l, 16, 0, 0);
}

// ---- unified prep: [0,64) Wp1T | [64,128) GvT | [128,192) AqT | [192,224) ga/ba | [224,226) gv/bv
__global__ __launch_bounds__(256) void prep_kernel(
    const float* __restrict__ Wp1, const float* __restrict__ Wkv,
    const float* __restrict__ g1, const float* __restrict__ b1,
    const float* __restrict__ cls, const float* __restrict__ Wq,
    unsigned short* __restrict__ Wp1T, unsigned short* __restrict__ GvT,
    unsigned short* __restrict__ AqT, float* __restrict__ gv, float* __restrict__ bv,
    float* __restrict__ ga, float* __restrict__ ba){
  const float SCALE = 0.17677669529663687f;
  const float LOGS  = 7.6246189861593985f;
  __shared__ float qred[32][9];
  __shared__ float q32[32];
  __shared__ unsigned short t[64][65];
  int bid = blockIdx.x;
  int tid = threadIdx.x;
  if (bid < 64){
    int c0 = (bid & 7) * 64, r0 = (bid >> 3) * 64;
    #pragma unroll
    for (int i = 0; i < 16; ++i){
      int idx = i * 256 + tid;
      int r = idx >> 6, c = idx & 63;
      t[c][r] = f2b(Wp1[(size_t)(r0 + r) * 512 + c0 + c]);
    }
    __syncthreads();
    #pragma unroll
    for (int i = 0; i < 16; ++i){
      int idx = i * 256 + tid;
      int r = idx >> 6, c = idx & 63;
      Wp1T[(size_t)(c0 + r) * 512 + r0 + c] = t[r][c];
    }
  } else if (bid < 128){
    int bx = bid - 64;
    int c0 = (bx & 7) * 64, r0 = (bx >> 3) * 64;
    #pragma unroll
    for (int i = 0; i < 16; ++i){
      int idx = i * 256 + tid;
      int r = idx >> 6, c = idx & 63;
      t[c][r] = f2b(Wkv[(size_t)(r0 + r) * 1024 + 512 + c0 + c] * g1[r0 + r]);
    }
    __syncthreads();
    #pragma unroll
    for (int i = 0; i < 16; ++i){
      int idx = i * 256 + tid;
      int r = idx >> 6, c = idx & 63;
      GvT[(size_t)(c0 + r) * 512 + r0 + c] = t[r][c];
    }
  } else if (bid < 224){
    // q32[hd] = sum_kd cls[n][kd] * Wq[kd][h*32+hd]  (in-block)
    int hn = (bid < 192) ? ((bid - 128) >> 1) : (bid - 192);
    int h = hn >> 1, n = hn & 1;
    {
      int hd = tid >> 3, part = tid & 7;
      float ps = 0.f;
      #pragma unroll 8
      for (int i = 0; i < 64; ++i){
        int kd = part * 64 + i;
        ps = fmaf(cls[n * 512 + kd], Wq[(size_t)kd * 512 + h * 32 + hd], ps);
      }
      qred[hd][part] = ps;
      __syncthreads();
      if (tid < 32){
        float s = 0.f;
        #pragma unroll
        for (int p = 0; p < 8; ++p) s += qred[tid][p];
        q32[tid] = s;
      }
      __syncthreads();
    }
    if (bid < 192){
      // AqT[hn][d] = SCALE * g1[d] * sum_hd Wkv[d][h*32+hd] * q32[hd]
      int d = ((bid - 128) & 1) * 256 + tid;
      float s = 0.f;
      #pragma unroll
      for (int hd = 0; hd < 32; ++hd)
        s = fmaf(Wkv[(size_t)d * 1024 + h * 32 + hd], q32[hd], s);
      AqT[hn * 512 + d] = f2b(SCALE * g1[d] * s);
    } else {
      // ga/ba[hn]
      __shared__ float red[8];
      float s1 = 0.f, s2 = 0.f;
      #pragma unroll
      for (int dd = 0; dd < 2; ++dd){
        int d = tid + dd * 256;
        float inner = 0.f;
        #pragma unroll
        for (int hd = 0; hd < 32; ++hd)
          inner = fmaf(Wkv[(size_t)d * 1024 + h * 32 + hd], q32[hd], inner);
        s1 = fmaf(g1[d], inner, s1);
        s2 = fmaf(b1[d], inner, s2);
      }
      #pragma unroll
      for (int off = 32; off; off >>= 1){
        s1 += __shfl_xor(s1, off, 64);
        s2 += __shfl_xor(s2, off, 64);
      }
      int w = tid >> 6, lane = tid & 63;
      if (lane == 0){ red[w * 2] = s1; red[w * 2 + 1] = s2; }
      __syncthreads();
      if (tid == 0){
        float t1 = red[0] + red[2] + red[4] + red[6];
        float t2 = red[1] + red[3] + red[5] + red[7];
        ga[hn] = SCALE * t1;
        ba[hn] = SCALE * t2 - LOGS;
      }
    }
  } else {
    int c = (bid - 224) * 256 + tid;     // 0..511
    float s1 = 0.f, s2 = 0.f;
    for (int d = 0; d < 512; ++d){
      float wv = Wkv[(size_t)d * 1024 + 512 + c];
      s1 = fmaf(g1[d], wv, s1);
      s2 = fmaf(b1[d], wv, s2);
    }
    gv[c] = s1; bv[c] = s2;
  }
}

// ---------------- conv v3 + inline wavelet taps: 16 rows x 256 ch, 4 blocks/CU ---------
__global__ __launch_bounds__(256) void conv_kernel(const float* __restrict__ X,
    const float* __restrict__ w1, const float* __restrict__ w2, const float* __restrict__ w3,
    unsigned short* __restrict__ Pos){
  __shared__ float xs[34 * 256];            // 34 KB
  int id = blockIdx.x;                      // 8192
  int id2 = (id & 7) * 1024 + (id >> 3);    // XCD-bijective
  int b = id2 >> 8;
  int rem = id2 & 255;
  int strip = rem >> 1, half = rem & 1;
  int s0 = strip * 16, c0 = half * 256;
  int tid = threadIdx.x;
  const float* xb = X + ((size_t)b * SEQ) * DIM + c0;
  #pragma unroll
  for (int i = 0; i < 9; ++i){
    int g = i * 256 + tid;
    if (g < 2176){
      int row = g >> 6;
      int gc = g & 63;
      int s = s0 - 9 + row;
      int sc = s < 0 ? 0 : (s > SEQ - 1 ? SEQ - 1 : s);
      gload16(xb + (size_t)sc * DIM + gc * 4, &xs[row * 256 + gc * 4]);
    }
  }
  // inline wavelet taps for channel c0+tid (overlaps the async stage)
  int d = tid;
  int dch = c0 + d;
  float kx[19];
  #pragma unroll
  for (int i = 0; i < 19; ++i) kx[i] = 0.f;
  const float C = 0.86732501f;
  const float* waves[3] = { w1, w2, w3 };
  #pragma unroll
  for (int tt = 0; tt < 3; ++tt){
    float scale = waves[tt][dch];
    float shift = waves[tt][DIM + dch];
    float inv = 1.f / scale;
    float amp = C * rsqrtf(fabsf(scale));
    #pragma unroll
    for (int i = 0; i < 19; ++i){
      float u = ((float)(i - 9) - shift) * inv;
      kx[i] += amp * (1.f - u * u) * expf(-0.5f * u * u);
    }
  }
  __syncthreads();
  if (strip == 0){
    #pragma unroll
    for (int i = 0; i < 9; ++i) xs[i * 256 + tid] = 0.f;
    __syncthreads();
  } else if (strip == 127){
    #pragma unroll
    for (int i = 25; i < 34; ++i) xs[i * 256 + tid] = 0.f;
    __syncthreads();
  }
  float ox[16];
  #pragma unroll
  for (int o = 0; o < 16; ++o) ox[o] = 0.f;
  #pragma unroll
  for (int w = 0; w < 34; ++w){
    float xv = xs[w * 256 + d];
    #pragma unroll
    for (int o = 0; o < 16; ++o){
      int t2 = w - o;
      if (t2 >= 0 && t2 < 19) ox[o] = fmaf(xv, kx[t2], ox[o]);
    }
  }
  #pragma unroll
  for (int o = 0; o < 16; ++o)
    Pos[((size_t)(b * SEQ + s0 + o)) * DIM + c0 + d] = f2b(ox[o]);
}

// ---------------- GEMM1: 128x128, 8 waves, low-reg; dbuf + counted vmcnt + swizzle -----
__global__ __launch_bounds__(512, 4) void gemm1_kernel(const unsigned short* __restrict__ A,
    const unsigned short* __restrict__ Bt, const float* __restrict__ Xres,
    const float* __restrict__ bias, unsigned short* __restrict__ Out,
    float* __restrict__ stat_part){
  __shared__ unsigned short lA[2 * 8192];    // 32 KB
  __shared__ unsigned short lB[2 * 8192];    // 32 KB
  __shared__ float sred[128][2][2];
  int tid = threadIdx.x;
  int w = tid >> 6, lane = tid & 63;
  int wm = w >> 1, wn = w & 1;
  int q = lane >> 4, cl = lane & 15;
  int id = blockIdx.x;                        // 2048
  int xcd = id & 7;
  int nch = (id >> 3) & 3;
  int mb  = ((id >> 5) << 3) | xcd;           // 0..511
  size_t mBase = (size_t)mb * 128;
  int nBase = nch * 128;

  auto stage = [&](int buf, int k0){
    #pragma unroll
    for (int p = 0; p < 2; ++p){
      int G = p * 512 + tid;
      int row = G >> 3;
      int c8 = (G & 7) ^ (row & 7);
      gload16(A + (mBase + row) * 512 + k0 + c8 * 8, &lA[buf * 8192 + G * 8]);
      gload16(Bt + (size_t)(nBase + row) * 512 + k0 + c8 * 8, &lB[buf * 8192 + G * 8]);
    }
  };

  f32x4 acc[2][4] = {};
  stage(0, 0);
  __syncthreads();
  int cur = 0;
  #pragma unroll
  for (int t = 0; t < 8; ++t){
    if (t < 7){
      stage(cur ^ 1, (t + 1) * 64);
      asm volatile("s_waitcnt vmcnt(4)" ::: "memory");
    } else {
      asm volatile("s_waitcnt vmcnt(0)" ::: "memory");
    }
    __builtin_amdgcn_s_barrier();
    const unsigned short* cA = &lA[cur * 8192];
    const unsigned short* cB = &lB[cur * 8192];
    #pragma unroll
    for (int kk = 0; kk < 2; ++kk){
      short8 af[2], bfr[4];
      #pragma unroll
      for (int m = 0; m < 2; ++m){
        int row = wm * 32 + m * 16 + cl;
        af[m] = *(const short8*)&cA[row * 64 + (((kk * 4 + q) ^ (row & 7)) * 8)];
      }
      #pragma unroll
      for (int n = 0; n < 4; ++n){
        int row = wn * 64 + n * 16 + cl;
        bfr[n] = *(const short8*)&cB[row * 64 + (((kk * 4 + q) ^ (row & 7)) * 8)];
      }
      #pragma unroll
      for (int m = 0; m < 2; ++m){
        #pragma unroll
        for (int n = 0; n < 4; ++n)
          acc[m][n] = __builtin_amdgcn_mfma_f32_16x16x32_bf16(af[m], bfr[n], acc[m][n], 0, 0, 0);
      }
    }
    asm volatile("s_waitcnt lgkmcnt(0)" ::: "memory");
    __builtin_amdgcn_s_barrier();
    cur ^= 1;
  }
  #pragma unroll
  for (int m = 0; m < 2; ++m){
    #pragma unroll
    for (int j = 0; j < 4; ++j){
      int rl = wm * 32 + m * 16 + q * 4 + j;
      size_t row = mBase + rl;
      float sm = 0.f, sq = 0.f;
      #pragma unroll
      for (int n = 0; n < 4; ++n){
        int col = nBase + wn * 64 + n * 16 + cl;
        float v = acc[m][n][j] + Xres[row * DIM + col] + bias[col];
        Out[row * DIM + col] = f2b(v);
        sm += v; sq += v * v;
      }
      #pragma unroll
      for (int off = 1; off < 16; off <<= 1){
        sm += __shfl_xor(sm, off, 64);
        sq += __shfl_xor(sq, off, 64);
      }
      if (cl == 0){ sred[rl][wn][0] = sm; sred[rl][wn][1] = sq; }
    }
  }
  __syncthreads();
  if (tid < 128){
    float sm = sred[tid][0][0] + sred[tid][1][0];
    float sq = sred[tid][0][1] + sred[tid][1][1];
    stat_part[((mBase + tid) * 4 + nch) * 2 + 0] = sm;
    stat_part[((mBase + tid) * 4 + nch) * 2 + 1] = sq;
  }
}

// ---------------- stage2: 8 waves, low-reg; AqT in B-tile (dup-write padding) ----------
__global__ __launch_bounds__(512, 4) void stage2_kernel(
    const unsigned short* __restrict__ Y, const unsigned short* __restrict__ GvT,
    const unsigned short* __restrict__ AqT, const float* __restrict__ stat_part,
    const float* __restrict__ gv, const float* __restrict__ bv,
    const float* __restrict__ ga, const float* __restrict__ ba,
    float* __restrict__ aout, float* __restrict__ o_part){
  __shared__ __align__(16) char smem[74752];
  unsigned short* lA = (unsigned short*)smem;               // 2 x 16 KB
  unsigned short* lB = (unsigned short*)(smem + 32768);     // 2 x 20 KB
  float* stats = (float*)(smem + 73728);                    // 1 KB
  float* attn_lds = (float*)smem;                           // overlay
  float* o_red = (float*)(smem + 16896);                    // overlay
  int tid = threadIdx.x;
  int w = tid >> 6, lane = tid & 63;
  int wm = w >> 1, wn = w & 1;
  int q = lane >> 4, cl = lane & 15;
  int id = blockIdx.x;                        // 2048
  int xcd = id & 7;
  int nch = (id >> 3) & 3;
  int mb  = ((id >> 5) << 3) | xcd;
  size_t mBase = (size_t)mb * 128;
  int nBase = nch * 128;

  auto stage = [&](int buf, int k0){
    #pragma unroll
    for (int p = 0; p < 2; ++p){
      int G = p * 512 + tid;
      int row = G >> 3;
      int c8 = (G & 7) ^ (row & 7);
      gload16(Y + (mBase + row) * 512 + k0 + c8 * 8, &lA[buf * 8192 + G * 8]);
      gload16(GvT + (size_t)(nBase + row) * 512 + k0 + c8 * 8, &lB[buf * 10240 + G * 8]);
    }
    {
      int g = tid & 255;
      int row = 128 + (g >> 3);
      int c8 = (g & 7) ^ (row & 7);
      gload16(AqT + (size_t)(row - 128) * 512 + k0 + c8 * 8, &lB[buf * 10240 + (1024 + g) * 8]);
    }
  };

  stage(0, 0);
  if (tid < 128){
    float sm = 0.f, sq = 0.f;
    #pragma unroll
    for (int i = 0; i < 4; ++i){
      sm += stat_part[((mBase + tid) * 4 + i) * 2 + 0];
      sq += stat_part[((mBase + tid) * 4 + i) * 2 + 1];
    }
    float mean = sm * (1.f / 512.f);
    float var = sq * (1.f / 512.f) - mean * mean;
    stats[tid * 2 + 0] = mean;
    stats[tid * 2 + 1] = rsqrtf(var + 1e-5f);
  }
  __syncthreads();

  int hn = wn * 16 + cl;
  f32x4 acc[2][4] = {};
  f32x4 accs[2] = {};
  int cur = 0;
  #pragma unroll
  for (int t = 0; t < 8; ++t){
    if (t < 7){
      stage(cur ^ 1, (t + 1) * 64);
      asm volatile("s_waitcnt vmcnt(5)" ::: "memory");
    } else {
      asm volatile("s_waitcnt vmcnt(0)" ::: "memory");
    }
    __builtin_amdgcn_s_barrier();
    const unsigned short* cA = &lA[cur * 8192];
    const unsigned short* cB = &lB[cur * 10240];
    #pragma unroll
    for (int kk = 0; kk < 2; ++kk){
      short8 af[2], bfr[4], bq;
      {
        int row = 128 + hn;
        bq = *(const short8*)&cB[row * 64 + (((kk * 4 + q) ^ (row & 7)) * 8)];
      }
      #pragma unroll
      for (int m = 0; m < 2; ++m){
        int row = wm * 32 + m * 16 + cl;
        af[m] = *(const short8*)&cA[row * 64 + (((kk * 4 + q) ^ (row & 7)) * 8)];
      }
      #pragma unroll
      for (int n = 0; n < 4; ++n){
        int row = wn * 64 + n * 16 + cl;
        bfr[n] = *(const short8*)&cB[row * 64 + (((kk * 4 + q) ^ (row & 7)) * 8)];
      }
      #pragma unroll
      for (int m = 0; m < 2; ++m){
        #pragma unroll
        for (int n = 0; n < 4; ++n)
          acc[m][n] = __builtin_amdgcn_mfma_f32_16x16x32_bf16(af[m], bfr[n], acc[m][n], 0, 0, 0);
        accs[m] = __builtin_amdgcn_mfma_f32_16x16x32_bf16(af[m], bq, accs[m], 0, 0, 0);
      }
    }
    asm volatile("s_waitcnt lgkmcnt(0)" ::: "memory");
    __builtin_amdgcn_s_barrier();
    cur ^= 1;
  }
  float gav = ga[hn], bav = ba[hn];
  float gv4[4], bv4[4];
  #pragma unroll
  for (int n = 0; n < 4; ++n){
    int cg = nBase + wn * 64 + n * 16 + cl;
    gv4[n] = gv[cg]; bv4[n] = bv[cg];
  }
  int b = mb >> 4;
  int scb = (mb & 15) * 128;
  #pragma unroll
  for (int m = 0; m < 2; ++m){
    #pragma unroll
    for (int j = 0; j < 4; ++j){
      int rl = wm * 32 + m * 16 + q * 4 + j;
      float mu = stats[rl * 2 + 0], s = stats[rl * 2 + 1];
      float sc = s * accs[m][j] - s * mu * gav + bav;
      float at = 1.f / (1.f + expf(-sc));
      attn_lds[rl * 33 + hn] = at;
      if (nch == 0)
        aout[((size_t)(b * NH + (hn >> 1)) * NCLS + (hn & 1)) * SEQ + scb + rl] = at;
      #pragma unroll
      for (int n = 0; n < 4; ++n)
        acc[m][n][j] = s * acc[m][n][j] - s * mu * gv4[n] + bv4[n];
    }
  }
  __syncthreads();
  float o0[4] = {}, o1[4] = {};
  #pragma unroll
  for (int n = 0; n < 4; ++n){
    int cg = nBase + wn * 64 + n * 16 + cl;
    int h2 = ((cg >> 5) << 1);
    #pragma unroll
    for (int m = 0; m < 2; ++m){
      #pragma unroll
      for (int j = 0; j < 4; ++j){
        int rl = wm * 32 + m * 16 + q * 4 + j;
        float vv = acc[m][n][j];
        o0[n] = fmaf(attn_lds[rl * 33 + h2 + 0], vv, o0[n]);
        o1[n] = fmaf(attn_lds[rl * 33 + h2 + 1], vv, o1[n]);
      }
    }
  }
  #pragma unroll
  for (int n = 0; n < 4; ++n){
    o0[n] += __shfl_xor(o0[n], 16, 64);
    o0[n] += __shfl_xor(o0[n], 32, 64);
    o1[n] += __shfl_xor(o1[n], 16, 64);
    o1[n] += __shfl_xor(o1[n], 32, 64);
  }
  if (q == 0){
    #pragma unroll
    for (int n = 0; n < 4; ++n){
      int c = wn * 64 + n * 16 + cl;
      o_red[(0 * 4 + wm) * 128 + c] = o0[n];
      o_red[(1 * 4 + wm) * 128 + c] = o1[n];
    }
  }
  __syncthreads();
  if (tid < 256){
    int nn = tid >> 7, c = tid & 127;
    float v = o_red[(nn * 4 + 0) * 128 + c] + o_red[(nn * 4 + 1) * 128 + c]
            + o_red[(nn * 4 + 2) * 128 + c] + o_red[(nn * 4 + 3) * 128 + c];
    o_part[((size_t)mb * 2 + nn) * 512 + nBase + c] = v;
  }
}

// ---------------- Head ----------------
__global__ __launch_bounds__(256) void head_kernel(const float* __restrict__ o_part,
    const float* __restrict__ Wproj, const float* __restrict__ bproj,
    const float* __restrict__ g2, const float* __restrict__ b2v,
    const float* __restrict__ Wc1, const float* __restrict__ bc1,
    const float* __restrict__ Wc2, const float* __restrict__ bc2,
    float* __restrict__ logits){
  __shared__ float orow[512];
  __shared__ float hrow[512];
  __shared__ float wred[8];
  __shared__ float wred2[4];
  int tid = threadIdx.x;
  int row = blockIdx.x;
  int b = row >> 1, nn = row & 1;
  for (int i = tid; i < 512; i += 256){
    float s = 0.f;
    const float* op = o_part + (((size_t)b * 16) * 2 + nn) * 512 + i;
    #pragma unroll
    for (int sc = 0; sc < 16; ++sc) s += op[(size_t)sc * 1024];
    orow[i] = s;
  }
  __syncthreads();
  int c0 = tid * 2;
  float a0 = 0.f, a1 = 0.f;
  for (int dd = 0; dd < DIM; ++dd){
    float ov = orow[dd];
    const float* wr = Wproj + (size_t)dd * DIM + c0;
    a0 = fmaf(ov, wr[0], a0);
    a1 = fmaf(ov, wr[1], a1);
  }
  a0 += bproj[c0]; a1 += bproj[c0 + 1];
  float sm = a0 + a1, sq = a0 * a0 + a1 * a1;
  #pragma unroll
  for (int off = 32; off; off >>= 1){
    sm += __shfl_xor(sm, off, 64);
    sq += __shfl_xor(sq, off, 64);
  }
  int w = tid >> 6, lane = tid & 63;
  if (lane == 0){ wred[w * 2] = sm; wred[w * 2 + 1] = sq; }
  __syncthreads();
  sm = wred[0] + wred[2] + wred[4] + wred[6];
  sq = wred[1] + wred[3] + wred[5] + wred[7];
  float mean = sm * (1.f / 512.f);
  float var = sq * (1.f / 512.f) - mean * mean;
  float rstd = rsqrtf(var + 1e-5f);
  hrow[c0]     = (a0 - mean) * rstd * g2[c0]     + b2v[c0];
  hrow[c0 + 1] = (a1 - mean) * rstd * g2[c0 + 1] + b2v[c0 + 1];
  __syncthreads();
  float h0 = 0.f, h1 = 0.f;
  for (int dd = 0; dd < DIM; ++dd){
    float lv = hrow[dd];
    const float* wr = Wc1 + (size_t)dd * DIM + c0;
    h0 = fmaf(lv, wr[0], h0);
    h1 = fmaf(lv, wr[1], h1);
  }
  h0 += bc1[c0]; h1 += bc1[c0 + 1];
  h0 = h0 > 0.f ? h0 : 0.f;
  h1 = h1 > 0.f ? h1 : 0.f;
  float p = h0 * Wc2[c0] + h1 * Wc2[c0 + 1];
  #pragma unroll
  for (int off = 32; off; off >>= 1) p += __shfl_xor(p, off, 64);
  if (lane == 0) wred2[w] = p;
  __syncthreads();
  if (tid == 0) logits[row] = wred2[0] + wred2[1] + wred2[2] + wred2[3] + bc2[0];
}

extern "C" void kernel_launch(void* const* d_in, const int* in_sizes, int n_in,
                              void* d_out, int out_size, void* d_ws, size_t ws_size,
                              hipStream_t stream) {
  const float* x     = (const float*)d_in[0];
  const float* wave1 = (const float*)d_in[1];
  const float* wave2 = (const float*)d_in[2];
  const float* wave3 = (const float*)d_in[3];
  const float* Wp1   = (const float*)d_in[4];
  const float* bp1   = (const float*)d_in[5];
  const float* cls   = (const float*)d_in[6];
  const float* ln1g  = (const float*)d_in[7];
  const float* ln1b  = (const float*)d_in[8];
  const float* Wq    = (const float*)d_in[9];
  const float* Wkv   = (const float*)d_in[10];
  const float* Wproj = (const float*)d_in[11];
  const float* bproj = (const float*)d_in[12];
  const float* ln2g  = (const float*)d_in[13];
  const float* ln2b  = (const float*)d_in[14];
  const float* Wc1   = (const float*)d_in[15];
  const float* bc1   = (const float*)d_in[16];
  const float* Wc2   = (const float*)d_in[17];
  const float* bc2   = (const float*)d_in[18];

  float* out = (float*)d_out;
  float* logits = out;
  float* attn   = out + 64;

  unsigned char* ws = (unsigned char*)d_ws;
  unsigned short* Wp1T  = (unsigned short*)(ws + (128u << 10));
  unsigned short* GvT   = (unsigned short*)(ws + (640u << 10));
  unsigned short* AqT   = (unsigned short*)(ws + (1152u << 10));
  float* gv             = (float*)(ws + (1248u << 10));
  float* bv             = (float*)(ws + (1252u << 10));
  float* ga             = (float*)(ws + (1256u << 10));
  float* ba             = (float*)(ws + (1260u << 10));
  float* o_part         = (float*)(ws + (1776u << 10));
  float* stat_part      = (float*)(ws + (4096u << 10));
  unsigned short* pos   = (unsigned short*)(ws + (8ull << 20));
  unsigned short* yb    = (unsigned short*)(ws + (72ull << 20));

  conv_kernel<<<dim3(8192), dim3(256), 0, stream>>>(x, wave1, wave2, wave3, pos);
  prep_kernel<<<dim3(226), dim3(256), 0, stream>>>(Wp1, Wkv, ln1g, ln1b, cls, Wq,
                                                   Wp1T, GvT, AqT, gv, bv, ga, ba);
  gemm1_kernel<<<dim3(2048), dim3(512), 0, stream>>>(pos, Wp1T, x, bp1, yb, stat_part);
  stage2_kernel<<<dim3(2048), dim3(512), 0, stream>>>(yb, GvT, AqT, stat_part,
                                                      gv, bv, ga, ba, attn, o_part);
  head_kernel<<<dim3(64), dim3(256), 0, stream>>>(o_part, Wproj, bproj, ln2g, ln2b,
                                                  Wc1, bc1, Wc2, bc2, logits);
}

// Round 16
// 237.986 us; speedup vs baseline: 1.1790x; 1.1790x over previous
//
#include <hip/hip_runtime.h>

#define SEQ 2048
#define DIM 512
#define NBATCH 32
#define NH 16
#define HDIM 32
#define NCLS 2

typedef __attribute__((ext_vector_type(8))) short short8;
typedef __attribute__((ext_vector_type(8))) unsigned short ushort8;
typedef __attribute__((ext_vector_type(4))) float f32x4;

__device__ __forceinline__ float b2f(unsigned short u){
  union { unsigned int i; float f; } v; v.i = ((unsigned int)u) << 16; return v.f;
}
__device__ __forceinline__ unsigned short f2b(float f){
  unsigned int x = __float_as_uint(f);
  unsigned int r = (x + 0x7fffu + ((x >> 16) & 1u)) >> 16;
  return (unsigned short)r;
}
__device__ __forceinline__ void gload16(const void* g, void* l){
  __builtin_amdgcn_global_load_lds((const __attribute__((address_space(1))) void*)g,
                                   (__attribute__((address_space(3))) void*)l, 16, 0, 0);
}

// ---- unified prep: [0,64) Wp1T | [64,128) GvT | [128,192) AqT | [192,224) ga/ba
//                    [224,226) gv/bv | [226,228) ksum
__global__ __launch_bounds__(256) void prep_kernel(
    const float* __restrict__ Wp1, const float* __restrict__ Wkv,
    const float* __restrict__ g1, const float* __restrict__ b1,
    const float* __restrict__ cls, const float* __restrict__ Wq,
    const float* __restrict__ w1, const float* __restrict__ w2, const float* __restrict__ w3,
    unsigned short* __restrict__ Wp1T, unsigned short* __restrict__ GvT,
    unsigned short* __restrict__ AqT, float* __restrict__ gv, float* __restrict__ bv,
    float* __restrict__ ga, float* __restrict__ ba, float* __restrict__ ksum){
  const float SCALE = 0.17677669529663687f;
  const float LOGS  = 7.6246189861593985f;
  __shared__ float qred[32][9];
  __shared__ float q32[32];
  __shared__ unsigned short t[64][65];
  int bid = blockIdx.x;
  int tid = threadIdx.x;
  if (bid < 64){
    int c0 = (bid & 7) * 64, r0 = (bid >> 3) * 64;
    #pragma unroll
    for (int i = 0; i < 16; ++i){
      int idx = i * 256 + tid;
      int r = idx >> 6, c = idx & 63;
      t[c][r] = f2b(Wp1[(size_t)(r0 + r) * 512 + c0 + c]);
    }
    __syncthreads();
    #pragma unroll
    for (int i = 0; i < 16; ++i){
      int idx = i * 256 + tid;
      int r = idx >> 6, c = idx & 63;
      Wp1T[(size_t)(c0 + r) * 512 + r0 + c] = t[r][c];
    }
  } else if (bid < 128){
    int bx = bid - 64;
    int c0 = (bx & 7) * 64, r0 = (bx >> 3) * 64;
    #pragma unroll
    for (int i = 0; i < 16; ++i){
      int idx = i * 256 + tid;
      int r = idx >> 6, c = idx & 63;
      t[c][r] = f2b(Wkv[(size_t)(r0 + r) * 1024 + 512 + c0 + c] * g1[r0 + r]);
    }
    __syncthreads();
    #pragma unroll
    for (int i = 0; i < 16; ++i){
      int idx = i * 256 + tid;
      int r = idx >> 6, c = idx & 63;
      GvT[(size_t)(c0 + r) * 512 + r0 + c] = t[r][c];
    }
  } else if (bid < 224){
    // q32[hd] = sum_kd cls[n][kd] * Wq[kd][h*32+hd]  (in-block)
    int hn = (bid < 192) ? ((bid - 128) >> 1) : (bid - 192);
    int h = hn >> 1, n = hn & 1;
    {
      int hd = tid >> 3, part = tid & 7;
      float ps = 0.f;
      #pragma unroll 8
      for (int i = 0; i < 64; ++i){
        int kd = part * 64 + i;
        ps = fmaf(cls[n * 512 + kd], Wq[(size_t)kd * 512 + h * 32 + hd], ps);
      }
      qred[hd][part] = ps;
      __syncthreads();
      if (tid < 32){
        float s = 0.f;
        #pragma unroll
        for (int p = 0; p < 8; ++p) s += qred[tid][p];
        q32[tid] = s;
      }
      __syncthreads();
    }
    if (bid < 192){
      int d = ((bid - 128) & 1) * 256 + tid;
      float s = 0.f;
      #pragma unroll
      for (int hd = 0; hd < 32; ++hd)
        s = fmaf(Wkv[(size_t)d * 1024 + h * 32 + hd], q32[hd], s);
      AqT[hn * 512 + d] = f2b(SCALE * g1[d] * s);
    } else {
      __shared__ float red[8];
      float s1 = 0.f, s2 = 0.f;
      #pragma unroll
      for (int dd = 0; dd < 2; ++dd){
        int d = tid + dd * 256;
        float inner = 0.f;
        #pragma unroll
        for (int hd = 0; hd < 32; ++hd)
          inner = fmaf(Wkv[(size_t)d * 1024 + h * 32 + hd], q32[hd], inner);
        s1 = fmaf(g1[d], inner, s1);
        s2 = fmaf(b1[d], inner, s2);
      }
      #pragma unroll
      for (int off = 32; off; off >>= 1){
        s1 += __shfl_xor(s1, off, 64);
        s2 += __shfl_xor(s2, off, 64);
      }
      int w = tid >> 6, lane = tid & 63;
      if (lane == 0){ red[w * 2] = s1; red[w * 2 + 1] = s2; }
      __syncthreads();
      if (tid == 0){
        float t1 = red[0] + red[2] + red[4] + red[6];
        float t2 = red[1] + red[3] + red[5] + red[7];
        ga[hn] = SCALE * t1;
        ba[hn] = SCALE * t2 - LOGS;
      }
    }
  } else if (bid < 226){
    int c = (bid - 224) * 256 + tid;     // 0..511
    float s1 = 0.f, s2 = 0.f;
    for (int d = 0; d < 512; ++d){
      float wv = Wkv[(size_t)d * 1024 + 512 + c];
      s1 = fmaf(g1[d], wv, s1);
      s2 = fmaf(b1[d], wv, s2);
    }
    gv[c] = s1; bv[c] = s2;
  } else {
    int d = (bid - 226) * 256 + tid;     // 0..511
    const float C = 0.86732501f;
    float acc[19];
    #pragma unroll
    for (int i = 0; i < 19; ++i) acc[i] = 0.f;
    const float* waves[3] = { w1, w2, w3 };
    for (int tt = 0; tt < 3; ++tt){
      float scale = waves[tt][d];
      float shift = waves[tt][DIM + d];
      float inv = 1.f / scale;
      float amp = C * rsqrtf(fabsf(scale));
      #pragma unroll
      for (int i = 0; i < 19; ++i){
        float u = ((float)(i - 9) - shift) * inv;
        acc[i] += amp * (1.f - u * u) * expf(-0.5f * u * u);
      }
    }
    #pragma unroll
    for (int i = 0; i < 19; ++i) ksum[i * DIM + d] = acc[i];
  }
}

// ---------------- conv v3: LDS-staged FIR, 16 rows x 256 ch, 4 blocks/CU ----------------
__global__ __launch_bounds__(256) void conv_kernel(const float* __restrict__ X,
    const float* __restrict__ ksum, unsigned short* __restrict__ Pos){
  __shared__ float xs[34 * 256];            // 34 KB
  int id = blockIdx.x;                      // 8192
  int id2 = (id & 7) * 1024 + (id >> 3);    // XCD-bijective
  int b = id2 >> 8;
  int rem = id2 & 255;
  int strip = rem >> 1, half = rem & 1;
  int s0 = strip * 16, c0 = half * 256;
  int tid = threadIdx.x;
  const float* xb = X + ((size_t)b * SEQ) * DIM + c0;
  #pragma unroll
  for (int i = 0; i < 9; ++i){
    int g = i * 256 + tid;
    if (g < 2176){
      int row = g >> 6;
      int gc = g & 63;
      int s = s0 - 9 + row;
      int sc = s < 0 ? 0 : (s > SEQ - 1 ? SEQ - 1 : s);
      gload16(xb + (size_t)sc * DIM + gc * 4, &xs[row * 256 + gc * 4]);
    }
  }
  __syncthreads();
  if (strip == 0){
    #pragma unroll
    for (int i = 0; i < 9; ++i) xs[i * 256 + tid] = 0.f;
    __syncthreads();
  } else if (strip == 127){
    #pragma unroll
    for (int i = 25; i < 34; ++i) xs[i * 256 + tid] = 0.f;
    __syncthreads();
  }
  int d = tid;
  float kx[19];
  #pragma unroll
  for (int t = 0; t < 19; ++t) kx[t] = ksum[t * DIM + c0 + d];
  float ox[16];
  #pragma unroll
  for (int o = 0; o < 16; ++o) ox[o] = 0.f;
  #pragma unroll
  for (int w = 0; w < 34; ++w){
    float xv = xs[w * 256 + d];
    #pragma unroll
    for (int o = 0; o < 16; ++o){
      int t2 = w - o;
      if (t2 >= 0 && t2 < 19) ox[o] = fmaf(xv, kx[t2], ox[o]);
    }
  }
  #pragma unroll
  for (int o = 0; o < 16; ++o)
    Pos[((size_t)(b * SEQ + s0 + o)) * DIM + c0 + d] = f2b(ox[o]);
}

// ---------------- GEMM1: 128x128, 8 waves, low-reg; dbuf + counted vmcnt + swizzle -----
__global__ __launch_bounds__(512, 4) void gemm1_kernel(const unsigned short* __restrict__ A,
    const unsigned short* __restrict__ Bt, const float* __restrict__ Xres,
    const float* __restrict__ bias, unsigned short* __restrict__ Out,
    float* __restrict__ stat_part){
  __shared__ unsigned short lA[2 * 8192];    // 32 KB
  __shared__ unsigned short lB[2 * 8192];    // 32 KB
  __shared__ float sred[128][2][2];
  int tid = threadIdx.x;
  int w = tid >> 6, lane = tid & 63;
  int wm = w >> 1, wn = w & 1;
  int q = lane >> 4, cl = lane & 15;
  int id = blockIdx.x;                        // 2048
  int xcd = id & 7;
  int nch = (id >> 3) & 3;
  int mb  = ((id >> 5) << 3) | xcd;           // 0..511
  size_t mBase = (size_t)mb * 128;
  int nBase = nch * 128;

  auto stage = [&](int buf, int k0){
    #pragma unroll
    for (int p = 0; p < 2; ++p){
      int G = p * 512 + tid;
      int row = G >> 3;
      int c8 = (G & 7) ^ (row & 7);
      gload16(A + (mBase + row) * 512 + k0 + c8 * 8, &lA[buf * 8192 + G * 8]);
      gload16(Bt + (size_t)(nBase + row) * 512 + k0 + c8 * 8, &lB[buf * 8192 + G * 8]);
    }
  };

  f32x4 acc[2][4] = {};
  stage(0, 0);
  __syncthreads();
  int cur = 0;
  #pragma unroll
  for (int t = 0; t < 8; ++t){
    if (t < 7){
      stage(cur ^ 1, (t + 1) * 64);
      asm volatile("s_waitcnt vmcnt(4)" ::: "memory");
    } else {
      asm volatile("s_waitcnt vmcnt(0)" ::: "memory");
    }
    __builtin_amdgcn_s_barrier();
    const unsigned short* cA = &lA[cur * 8192];
    const unsigned short* cB = &lB[cur * 8192];
    #pragma unroll
    for (int kk = 0; kk < 2; ++kk){
      short8 af[2], bfr[4];
      #pragma unroll
      for (int m = 0; m < 2; ++m){
        int row = wm * 32 + m * 16 + cl;
        af[m] = *(const short8*)&cA[row * 64 + (((kk * 4 + q) ^ (row & 7)) * 8)];
      }
      #pragma unroll
      for (int n = 0; n < 4; ++n){
        int row = wn * 64 + n * 16 + cl;
        bfr[n] = *(const short8*)&cB[row * 64 + (((kk * 4 + q) ^ (row & 7)) * 8)];
      }
      #pragma unroll
      for (int m = 0; m < 2; ++m){
        #pragma unroll
        for (int n = 0; n < 4; ++n)
          acc[m][n] = __builtin_amdgcn_mfma_f32_16x16x32_bf16(af[m], bfr[n], acc[m][n], 0, 0, 0);
      }
    }
    asm volatile("s_waitcnt lgkmcnt(0)" ::: "memory");
    __builtin_amdgcn_s_barrier();
    cur ^= 1;
  }
  #pragma unroll
  for (int m = 0; m < 2; ++m){
    #pragma unroll
    for (int j = 0; j < 4; ++j){
      int rl = wm * 32 + m * 16 + q * 4 + j;
      size_t row = mBase + rl;
      float sm = 0.f, sq = 0.f;
      #pragma unroll
      for (int n = 0; n < 4; ++n){
        int col = nBase + wn * 64 + n * 16 + cl;
        float v = acc[m][n][j] + Xres[row * DIM + col] + bias[col];
        Out[row * DIM + col] = f2b(v);
        sm += v; sq += v * v;
      }
      #pragma unroll
      for (int off = 1; off < 16; off <<= 1){
        sm += __shfl_xor(sm, off, 64);
        sq += __shfl_xor(sq, off, 64);
      }
      if (cl == 0){ sred[rl][wn][0] = sm; sred[rl][wn][1] = sq; }
    }
  }
  __syncthreads();
  if (tid < 128){
    float sm = sred[tid][0][0] + sred[tid][1][0];
    float sq = sred[tid][0][1] + sred[tid][1][1];
    stat_part[((mBase + tid) * 4 + nch) * 2 + 0] = sm;
    stat_part[((mBase + tid) * 4 + nch) * 2 + 1] = sq;
  }
}

// ---------------- stage2: 8 waves, low-reg; AqT in B-tile (dup-write padding) ----------
__global__ __launch_bounds__(512, 4) void stage2_kernel(
    const unsigned short* __restrict__ Y, const unsigned short* __restrict__ GvT,
    const unsigned short* __restrict__ AqT, const float* __restrict__ stat_part,
    const float* __restrict__ gv, const float* __restrict__ bv,
    const float* __restrict__ ga, const float* __restrict__ ba,
    float* __restrict__ aout, float* __restrict__ o_part){
  __shared__ __align__(16) char smem[74752];
  unsigned short* lA = (unsigned short*)smem;               // 2 x 16 KB
  unsigned short* lB = (unsigned short*)(smem + 32768);     // 2 x 20 KB
  float* stats = (float*)(smem + 73728);                    // 1 KB
  float* attn_lds = (float*)smem;                           // overlay
  float* o_red = (float*)(smem + 16896);                    // overlay
  int tid = threadIdx.x;
  int w = tid >> 6, lane = tid & 63;
  int wm = w >> 1, wn = w & 1;
  int q = lane >> 4, cl = lane & 15;
  int id = blockIdx.x;                        // 2048
  int xcd = id & 7;
  int nch = (id >> 3) & 3;
  int mb  = ((id >> 5) << 3) | xcd;
  size_t mBase = (size_t)mb * 128;
  int nBase = nch * 128;

  auto stage = [&](int buf, int k0){
    #pragma unroll
    for (int p = 0; p < 2; ++p){
      int G = p * 512 + tid;
      int row = G >> 3;
      int c8 = (G & 7) ^ (row & 7);
      gload16(Y + (mBase + row) * 512 + k0 + c8 * 8, &lA[buf * 8192 + G * 8]);
      gload16(GvT + (size_t)(nBase + row) * 512 + k0 + c8 * 8, &lB[buf * 10240 + G * 8]);
    }
    {
      int g = tid & 255;
      int row = 128 + (g >> 3);
      int c8 = (g & 7) ^ (row & 7);
      gload16(AqT + (size_t)(row - 128) * 512 + k0 + c8 * 8, &lB[buf * 10240 + (1024 + g) * 8]);
    }
  };

  stage(0, 0);
  if (tid < 128){
    float sm = 0.f, sq = 0.f;
    #pragma unroll
    for (int i = 0; i < 4; ++i){
      sm += stat_part[((mBase + tid) * 4 + i) * 2 + 0];
      sq += stat_part[((mBase + tid) * 4 + i) * 2 + 1];
    }
    float mean = sm * (1.f / 512.f);
    float var = sq * (1.f / 512.f) - mean * mean;
    stats[tid * 2 + 0] = mean;
    stats[tid * 2 + 1] = rsqrtf(var + 1e-5f);
  }
  __syncthreads();

  int hn = wn * 16 + cl;
  f32x4 acc[2][4] = {};
  f32x4 accs[2] = {};
  int cur = 0;
  #pragma unroll
  for (int t = 0; t < 8; ++t){
    if (t < 7){
      stage(cur ^ 1, (t + 1) * 64);
      asm volatile("s_waitcnt vmcnt(5)" ::: "memory");
    } else {
      asm volatile("s_waitcnt vmcnt(0)" ::: "memory");
    }
    __builtin_amdgcn_s_barrier();
    const unsigned short* cA = &lA[cur * 8192];
    const unsigned short* cB = &lB[cur * 10240];
    #pragma unroll
    for (int kk = 0; kk < 2; ++kk){
      short8 af[2], bfr[4], bq;
      {
        int row = 128 + hn;
        bq = *(const short8*)&cB[row * 64 + (((kk * 4 + q) ^ (row & 7)) * 8)];
      }
      #pragma unroll
      for (int m = 0; m < 2; ++m){
        int row = wm * 32 + m * 16 + cl;
        af[m] = *(const short8*)&cA[row * 64 + (((kk * 4 + q) ^ (row & 7)) * 8)];
      }
      #pragma unroll
      for (int n = 0; n < 4; ++n){
        int row = wn * 64 + n * 16 + cl;
        bfr[n] = *(const short8*)&cB[row * 64 + (((kk * 4 + q) ^ (row & 7)) * 8)];
      }
      #pragma unroll
      for (int m = 0; m < 2; ++m){
        #pragma unroll
        for (int n = 0; n < 4; ++n)
          acc[m][n] = __builtin_amdgcn_mfma_f32_16x16x32_bf16(af[m], bfr[n], acc[m][n], 0, 0, 0);
        accs[m] = __builtin_amdgcn_mfma_f32_16x16x32_bf16(af[m], bq, accs[m], 0, 0, 0);
      }
    }
    asm volatile("s_waitcnt lgkmcnt(0)" ::: "memory");
    __builtin_amdgcn_s_barrier();
    cur ^= 1;
  }
  float gav = ga[hn], bav = ba[hn];
  float gv4[4], bv4[4];
  #pragma unroll
  for (int n = 0; n < 4; ++n){
    int cg = nBase + wn * 64 + n * 16 + cl;
    gv4[n] = gv[cg]; bv4[n] = bv[cg];
  }
  int b = mb >> 4;
  int scb = (mb & 15) * 128;
  #pragma unroll
  for (int m = 0; m < 2; ++m){
    #pragma unroll
    for (int j = 0; j < 4; ++j){
      int rl = wm * 32 + m * 16 + q * 4 + j;
      float mu = stats[rl * 2 + 0], s = stats[rl * 2 + 1];
      float sc = s * accs[m][j] - s * mu * gav + bav;
      float at = 1.f / (1.f + expf(-sc));
      attn_lds[rl * 33 + hn] = at;
      if (nch == 0)
        aout[((size_t)(b * NH + (hn >> 1)) * NCLS + (hn & 1)) * SEQ + scb + rl] = at;
      #pragma unroll
      for (int n = 0; n < 4; ++n)
        acc[m][n][j] = s * acc[m][n][j] - s * mu * gv4[n] + bv4[n];
    }
  }
  __syncthreads();
  float o0[4] = {}, o1[4] = {};
  #pragma unroll
  for (int n = 0; n < 4; ++n){
    int cg = nBase + wn * 64 + n * 16 + cl;
    int h2 = ((cg >> 5) << 1);
    #pragma unroll
    for (int m = 0; m < 2; ++m){
      #pragma unroll
      for (int j = 0; j < 4; ++j){
        int rl = wm * 32 + m * 16 + q * 4 + j;
        float vv = acc[m][n][j];
        o0[n] = fmaf(attn_lds[rl * 33 + h2 + 0], vv, o0[n]);
        o1[n] = fmaf(attn_lds[rl * 33 + h2 + 1], vv, o1[n]);
      }
    }
  }
  #pragma unroll
  for (int n = 0; n < 4; ++n){
    o0[n] += __shfl_xor(o0[n], 16, 64);
    o0[n] += __shfl_xor(o0[n], 32, 64);
    o1[n] += __shfl_xor(o1[n], 16, 64);
    o1[n] += __shfl_xor(o1[n], 32, 64);
  }
  if (q == 0){
    #pragma unroll
    for (int n = 0; n < 4; ++n){
      int c = wn * 64 + n * 16 + cl;
      o_red[(0 * 4 + wm) * 128 + c] = o0[n];
      o_red[(1 * 4 + wm) * 128 + c] = o1[n];
    }
  }
  __syncthreads();
  if (tid < 256){
    int nn = tid >> 7, c = tid & 127;
    float v = o_red[(nn * 4 + 0) * 128 + c] + o_red[(nn * 4 + 1) * 128 + c]
            + o_red[(nn * 4 + 2) * 128 + c] + o_red[(nn * 4 + 3) * 128 + c];
    o_part[((size_t)mb * 2 + nn) * 512 + nBase + c] = v;
  }
}

// ---------------- Head ----------------
__global__ __launch_bounds__(256) void head_kernel(const float* __restrict__ o_part,
    const float* __restrict__ Wproj, const float* __restrict__ bproj,
    const float* __restrict__ g2, const float* __restrict__ b2v,
    const float* __restrict__ Wc1, const float* __restrict__ bc1,
    const float* __restrict__ Wc2, const float* __restrict__ bc2,
    float* __restrict__ logits){
  __shared__ float orow[512];
  __shared__ float hrow[512];
  __shared__ float wred[8];
  __shared__ float wred2[4];
  int tid = threadIdx.x;
  int row = blockIdx.x;
  int b = row >> 1, nn = row & 1;
  for (int i = tid; i < 512; i += 256){
    float s = 0.f;
    const float* op = o_part + (((size_t)b * 16) * 2 + nn) * 512 + i;
    #pragma unroll
    for (int sc = 0; sc < 16; ++sc) s += op[(size_t)sc * 1024];
    orow[i] = s;
  }
  __syncthreads();
  int c0 = tid * 2;
  float a0 = 0.f, a1 = 0.f;
  for (int dd = 0; dd < DIM; ++dd){
    float ov = orow[dd];
    const float* wr = Wproj + (size_t)dd * DIM + c0;
    a0 = fmaf(ov, wr[0], a0);
    a1 = fmaf(ov, wr[1], a1);
  }
  a0 += bproj[c0]; a1 += bproj[c0 + 1];
  float sm = a0 + a1, sq = a0 * a0 + a1 * a1;
  #pragma unroll
  for (int off = 32; off; off >>= 1){
    sm += __shfl_xor(sm, off, 64);
    sq += __shfl_xor(sq, off, 64);
  }
  int w = tid >> 6, lane = tid & 63;
  if (lane == 0){ wred[w * 2] = sm; wred[w * 2 + 1] = sq; }
  __syncthreads();
  sm = wred[0] + wred[2] + wred[4] + wred[6];
  sq = wred[1] + wred[3] + wred[5] + wred[7];
  float mean = sm * (1.f / 512.f);
  float var = sq * (1.f / 512.f) - mean * mean;
  float rstd = rsqrtf(var + 1e-5f);
  hrow[c0]     = (a0 - mean) * rstd * g2[c0]     + b2v[c0];
  hrow[c0 + 1] = (a1 - mean) * rstd * g2[c0 + 1] + b2v[c0 + 1];
  __syncthreads();
  float h0 = 0.f, h1 = 0.f;
  for (int dd = 0; dd < DIM; ++dd){
    float lv = hrow[dd];
    const float* wr = Wc1 + (size_t)dd * DIM + c0;
    h0 = fmaf(lv, wr[0], h0);
    h1 = fmaf(lv, wr[1], h1);
  }
  h0 += bc1[c0]; h1 += bc1[c0 + 1];
  h0 = h0 > 0.f ? h0 : 0.f;
  h1 = h1 > 0.f ? h1 : 0.f;
  float p = h0 * Wc2[c0] + h1 * Wc2[c0 + 1];
  #pragma unroll
  for (int off = 32; off; off >>= 1) p += __shfl_xor(p, off, 64);
  if (lane == 0) wred2[w] = p;
  __syncthreads();
  if (tid == 0) logits[row] = wred2[0] + wred2[1] + wred2[2] + wred2[3] + bc2[0];
}

extern "C" void kernel_launch(void* const* d_in, const int* in_sizes, int n_in,
                              void* d_out, int out_size, void* d_ws, size_t ws_size,
                              hipStream_t stream) {
  const float* x     = (const float*)d_in[0];
  const float* wave1 = (const float*)d_in[1];
  const float* wave2 = (const float*)d_in[2];
  const float* wave3 = (const float*)d_in[3];
  const float* Wp1   = (const float*)d_in[4];
  const float* bp1   = (const float*)d_in[5];
  const float* cls   = (const float*)d_in[6];
  const float* ln1g  = (const float*)d_in[7];
  const float* ln1b  = (const float*)d_in[8];
  const float* Wq    = (const float*)d_in[9];
  const float* Wkv   = (const float*)d_in[10];
  const float* Wproj = (const float*)d_in[11];
  const float* bproj = (const float*)d_in[12];
  const float* ln2g  = (const float*)d_in[13];
  const float* ln2b  = (const float*)d_in[14];
  const float* Wc1   = (const float*)d_in[15];
  const float* bc1   = (const float*)d_in[16];
  const float* Wc2   = (const float*)d_in[17];
  const float* bc2   = (const float*)d_in[18];

  float* out = (float*)d_out;
  float* logits = out;
  float* attn   = out + 64;

  unsigned char* ws = (unsigned char*)d_ws;
  float* ksum           = (float*)(ws);
  unsigned short* Wp1T  = (unsigned short*)(ws + (128u << 10));
  unsigned short* GvT   = (unsigned short*)(ws + (640u << 10));
  unsigned short* AqT   = (unsigned short*)(ws + (1152u << 10));
  float* gv             = (float*)(ws + (1248u << 10));
  float* bv             = (float*)(ws + (1252u << 10));
  float* ga             = (float*)(ws + (1256u << 10));
  float* ba             = (float*)(ws + (1260u << 10));
  float* o_part         = (float*)(ws + (1776u << 10));
  float* stat_part      = (float*)(ws + (4096u << 10));
  unsigned short* pos   = (unsigned short*)(ws + (8ull << 20));
  unsigned short* yb    = (unsigned short*)(ws + (72ull << 20));

  prep_kernel<<<dim3(228), dim3(256), 0, stream>>>(Wp1, Wkv, ln1g, ln1b, cls, Wq,
                                                   wave1, wave2, wave3,
                                                   Wp1T, GvT, AqT, gv, bv, ga, ba, ksum);
  conv_kernel<<<dim3(8192), dim3(256), 0, stream>>>(x, ksum, pos);
  gemm1_kernel<<<dim3(2048), dim3(512), 0, stream>>>(pos, Wp1T, x, bp1, yb, stat_part);
  stage2_kernel<<<dim3(2048), dim3(512), 0, stream>>>(yb, GvT, AqT, stat_part,
                                                      gv, bv, ga, ba, attn, o_part);
  head_kernel<<<dim3(64), dim3(256), 0, stream>>>(o_part, Wproj, bproj, ln2g, ln2b,
                                                  Wc1, bc1, Wc2, bc2, logits);
}